// Round 1
// baseline (4430.737 us; speedup 1.0000x reference)
//
#include <hip/hip_runtime.h>
#include <math.h>

#define DD   128
#define NV   4000
#define NL   8000
#define NC   16000
#define TSTEPS 8
#define ROWW 96    // max clauses per literal (mean 40, std 6.3 -> huge margin)
#define COLW 64    // max literals per clause (mean 20, std 4.4 -> huge margin)

__device__ __forceinline__ float frcp(float x) {
#if __has_builtin(__builtin_amdgcn_rcpf)
  return __builtin_amdgcn_rcpf(x);
#else
  return 1.f / x;
#endif
}
__device__ __forceinline__ float sigm(float x) {
  // x<<0: exp(-x)=inf -> rcp=0 ; x>>0: exp(-x)=0 -> 1
  return frcp(1.f + __expf(-x));
}
__device__ __forceinline__ float tanh_(float x) {
  // 1 - 2/(e^{2x}+1): saturates correctly at +/-inf
  float e = __expf(2.f * x);
  return 1.f - 2.f * frcp(e + 1.f);
}
__device__ __forceinline__ void add4(float4& a, const float4 b) {
  a.x += b.x; a.y += b.y; a.z += b.z; a.w += b.w;
}

// ---------------- preprocessing kernels ----------------

__global__ __launch_bounds__(256) void copy_f4(float4* __restrict__ dst, const float4* __restrict__ src, int n4) {
  int stride = gridDim.x * blockDim.x;
  for (int i = blockIdx.x * blockDim.x + threadIdx.x; i < n4; i += stride) dst[i] = src[i];
}

// dst[k*J + j] = src[j*K + k]
__global__ __launch_bounds__(256) void transpose_into(float* __restrict__ dst, const float* __restrict__ src, int J, int K) {
  int i = blockIdx.x * blockDim.x + threadIdx.x;
  if (i >= J * K) return;
  int j = i / K, k = i - j * K;
  dst[k * J + j] = src[i];
}

// one pass over M (512 MB): build padded-ELL both directions
__global__ __launch_bounds__(256) void scan_M(const float4* __restrict__ M4,
                                              int* __restrict__ csr, int* __restrict__ csc,
                                              int* __restrict__ rcnt, int* __restrict__ ccnt) {
  const int total = (NL * NC) / 4;  // 32M float4
  int stride = gridDim.x * blockDim.x;
  for (int i = blockIdx.x * blockDim.x + threadIdx.x; i < total; i += stride) {
    float4 v = M4[i];
    if (v.x == 0.f && v.y == 0.f && v.z == 0.f && v.w == 0.f) continue;
    int base = i * 4;              // NC % 4 == 0 -> all 4 elems share the row
    int l = base / NC;
    int c0 = base - l * NC;
    float vv[4] = {v.x, v.y, v.z, v.w};
    #pragma unroll
    for (int e = 0; e < 4; ++e) {
      if (vv[e] != 0.f) {
        int c = c0 + e;
        int rp = atomicAdd(&rcnt[l], 1);
        if (rp < ROWW) csr[l * ROWW + rp] = c;
        int cp = atomicAdd(&ccnt[c], 1);
        if (cp < COLW) csc[c * COLW + cp] = l;
      }
    }
  }
}

// Y(rows x 128) = X(rows x 128) @ Wt(128x128, already transposed: Wt[k][j]) + b
__global__ __launch_bounds__(256) void gemm128(const float* __restrict__ X, const float* __restrict__ Wt,
                                               const float* __restrict__ b, float* __restrict__ Y) {
  __shared__ float xs[32 * 128];
  const int t = threadIdx.x;
  const int rowBase = blockIdx.x * 32;
  for (int ii = t; ii < 32 * 32; ii += 256)
    ((float4*)xs)[ii] = ((const float4*)(X + (size_t)rowBase * DD))[ii];
  __syncthreads();
  const int jg = t & 63, rg = t >> 6;   // 4 row-groups x 8 rows ; 64 j-groups x 2 cols
  const int j0 = jg * 2;
  float acc[8][2];
  #pragma unroll
  for (int rr = 0; rr < 8; ++rr) { acc[rr][0] = 0.f; acc[rr][1] = 0.f; }
  #pragma unroll 2
  for (int k = 0; k < 128; ++k) {
    const float2 w = *(const float2*)(Wt + k * 128 + j0);
    #pragma unroll
    for (int rr = 0; rr < 8; ++rr) {
      float x = xs[(rg * 8 + rr) * 128 + k];
      acc[rr][0] = fmaf(x, w.x, acc[rr][0]);
      acc[rr][1] = fmaf(x, w.y, acc[rr][1]);
    }
  }
  float b0 = b[j0], b1 = b[j0 + 1];
  #pragma unroll
  for (int rr = 0; rr < 8; ++rr)
    *(float2*)(Y + (size_t)(rowBase + rg * 8 + rr) * DD + j0) = make_float2(acc[rr][0] + b0, acc[rr][1] + b1);
}

// ---------------- per-step fused kernels ----------------
// clause update: x = gather(LC_pre), gates = [x|hC] @ WCt + b, LSTM (h=c=hC),
// hC <- c_new, CL_pre <- h_new @ Wcl^T + bcl
__global__ __launch_bounds__(256) void clause_step(
    const float* __restrict__ LCp, const int* __restrict__ csc, const int* __restrict__ ccnt,
    const float* __restrict__ WCt, const float* __restrict__ bih, const float* __restrict__ bhh,
    const float* __restrict__ Wclt, const float* __restrict__ bcl,
    float* __restrict__ hC, float* __restrict__ CLp) {
  __shared__ float xh[32 * 256];   // [row][0:128)=x msgs, [128:256)=h(=c_old)
  const int t = threadIdx.x;
  const int rowBase = blockIdx.x * 32;

  { // gather: 8 threads/row, 16 cols (4 float4) each
    const int r = t >> 3, cg = t & 7;
    const int c = rowBase + r;
    int cnt = ccnt[c]; if (cnt > COLW) cnt = COLW;
    const int* lst = csc + c * COLW;
    float4 a0 = make_float4(0,0,0,0), a1 = a0, a2 = a0, a3 = a0;
    for (int j = 0; j < cnt; ++j) {
      const float4* s = (const float4*)(LCp + (size_t)lst[j] * DD) + (cg << 2);
      add4(a0, s[0]); add4(a1, s[1]); add4(a2, s[2]); add4(a3, s[3]);
    }
    float4* dst = (float4*)(xh + r * 256) + (cg << 2);
    dst[0] = a0; dst[1] = a1; dst[2] = a2; dst[3] = a3;
  }
  for (int ii = t; ii < 32 * 32; ii += 256) {  // stage hC rows
    int r = ii >> 5, q = ii & 31;
    ((float4*)(xh + r * 256 + 128))[q] = ((const float4*)(hC + (size_t)(rowBase + r) * DD))[q];
  }
  __syncthreads();

  const int jg = t & 63, rg = t >> 6;
  const int j0 = jg * 2;
  float acc[8][4][2];
  #pragma unroll
  for (int rr = 0; rr < 8; ++rr)
    #pragma unroll
    for (int gt = 0; gt < 4; ++gt) { acc[rr][gt][0] = 0.f; acc[rr][gt][1] = 0.f; }

  #pragma unroll 2
  for (int k = 0; k < 256; ++k) {
    float xv[8];
    #pragma unroll
    for (int rr = 0; rr < 8; ++rr) xv[rr] = xh[(rg * 8 + rr) * 256 + k];
    #pragma unroll
    for (int gt = 0; gt < 4; ++gt) {
      const float2 w = *(const float2*)(WCt + k * 512 + gt * 128 + j0);
      #pragma unroll
      for (int rr = 0; rr < 8; ++rr) {
        acc[rr][gt][0] = fmaf(xv[rr], w.x, acc[rr][gt][0]);
        acc[rr][gt][1] = fmaf(xv[rr], w.y, acc[rr][gt][1]);
      }
    }
  }

  float bi[4][2];
  #pragma unroll
  for (int gt = 0; gt < 4; ++gt) {
    bi[gt][0] = bih[gt * 128 + j0]     + bhh[gt * 128 + j0];
    bi[gt][1] = bih[gt * 128 + j0 + 1] + bhh[gt * 128 + j0 + 1];
  }
  float hn[8][2];
  #pragma unroll
  for (int rr = 0; rr < 8; ++rr) {
    const int r = rg * 8 + rr;
    float c0 = xh[r * 256 + 128 + j0], c1 = xh[r * 256 + 128 + j0 + 1];
    float i0 = acc[rr][0][0] + bi[0][0], i1 = acc[rr][0][1] + bi[0][1];
    float f0 = acc[rr][1][0] + bi[1][0], f1 = acc[rr][1][1] + bi[1][1];
    float g0 = acc[rr][2][0] + bi[2][0], g1 = acc[rr][2][1] + bi[2][1];
    float o0 = acc[rr][3][0] + bi[3][0], o1 = acc[rr][3][1] + bi[3][1];
    float cn0 = sigm(f0) * c0 + sigm(i0) * tanh_(g0);
    float cn1 = sigm(f1) * c1 + sigm(i1) * tanh_(g1);
    hn[rr][0] = sigm(o0) * tanh_(cn0);
    hn[rr][1] = sigm(o1) * tanh_(cn1);
    *(float2*)(hC + (size_t)(rowBase + r) * DD + j0) = make_float2(cn0, cn1);
  }
  __syncthreads();
  #pragma unroll
  for (int rr = 0; rr < 8; ++rr)
    *(float2*)(xh + (rg * 8 + rr) * 256 + j0) = make_float2(hn[rr][0], hn[rr][1]);
  __syncthreads();

  float a2[8][2];
  #pragma unroll
  for (int rr = 0; rr < 8; ++rr) { a2[rr][0] = 0.f; a2[rr][1] = 0.f; }
  #pragma unroll 2
  for (int k = 0; k < 128; ++k) {
    const float2 w = *(const float2*)(Wclt + k * 128 + j0);
    #pragma unroll
    for (int rr = 0; rr < 8; ++rr) {
      float x = xh[(rg * 8 + rr) * 256 + k];
      a2[rr][0] = fmaf(x, w.x, a2[rr][0]);
      a2[rr][1] = fmaf(x, w.y, a2[rr][1]);
    }
  }
  float b0 = bcl[j0], b1 = bcl[j0 + 1];
  #pragma unroll
  for (int rr = 0; rr < 8; ++rr)
    *(float2*)(CLp + (size_t)(rowBase + rg * 8 + rr) * DD + j0) = make_float2(a2[rr][0] + b0, a2[rr][1] + b1);
}

// literal update: msg = gather(CL_pre); inp=[msg|L]; gates = [inp|hL] @ WLt + b (K=384),
// LSTM (h=c=hL); L <- h_new (in d_out), hL <- c_new, LC_pre <- h_new @ Wlc^T + blc
__global__ __launch_bounds__(256) void literal_step(
    const float* __restrict__ CLp, const int* __restrict__ csr, const int* __restrict__ rcnt,
    const float* __restrict__ WLt, const float* __restrict__ bih, const float* __restrict__ bhh,
    const float* __restrict__ Wlct, const float* __restrict__ blc,
    float* __restrict__ hL, float* __restrict__ Lbuf, float* __restrict__ LCp) {
  __shared__ float xh[16 * 384];  // [row][0:128)=msg, [128:256)=L, [256:384)=hL(=c_old)
  const int t = threadIdx.x;
  const int rowBase = blockIdx.x * 16;

  { // gather: 16 threads/row, 8 cols (2 float4) each
    const int r = t >> 4, cg = t & 15;
    const int l = rowBase + r;
    int cnt = rcnt[l]; if (cnt > ROWW) cnt = ROWW;
    const int* lst = csr + l * ROWW;
    float4 a0 = make_float4(0,0,0,0), a1 = a0;
    for (int j = 0; j < cnt; ++j) {
      const float4* s = (const float4*)(CLp + (size_t)lst[j] * DD) + (cg << 1);
      add4(a0, s[0]); add4(a1, s[1]);
    }
    float4* dst = (float4*)(xh + r * 384) + (cg << 1);
    dst[0] = a0; dst[1] = a1;
  }
  for (int ii = t; ii < 16 * 64; ii += 256) {  // stage L | hL
    int r = ii >> 6, q = ii & 63;
    float4 v;
    if (q < 32) v = ((const float4*)(Lbuf + (size_t)(rowBase + r) * DD))[q];
    else        v = ((const float4*)(hL   + (size_t)(rowBase + r) * DD))[q - 32];
    ((float4*)(xh + r * 384 + 128))[q] = v;
  }
  __syncthreads();

  const int jg = t & 63, rg = t >> 6;   // 4 row-groups x 4 rows
  const int j0 = jg * 2;
  float acc[4][4][2];
  #pragma unroll
  for (int rr = 0; rr < 4; ++rr)
    #pragma unroll
    for (int gt = 0; gt < 4; ++gt) { acc[rr][gt][0] = 0.f; acc[rr][gt][1] = 0.f; }

  #pragma unroll 2
  for (int k = 0; k < 384; ++k) {
    float xv[4];
    #pragma unroll
    for (int rr = 0; rr < 4; ++rr) xv[rr] = xh[(rg * 4 + rr) * 384 + k];
    #pragma unroll
    for (int gt = 0; gt < 4; ++gt) {
      const float2 w = *(const float2*)(WLt + k * 512 + gt * 128 + j0);
      #pragma unroll
      for (int rr = 0; rr < 4; ++rr) {
        acc[rr][gt][0] = fmaf(xv[rr], w.x, acc[rr][gt][0]);
        acc[rr][gt][1] = fmaf(xv[rr], w.y, acc[rr][gt][1]);
      }
    }
  }

  float bi[4][2];
  #pragma unroll
  for (int gt = 0; gt < 4; ++gt) {
    bi[gt][0] = bih[gt * 128 + j0]     + bhh[gt * 128 + j0];
    bi[gt][1] = bih[gt * 128 + j0 + 1] + bhh[gt * 128 + j0 + 1];
  }
  float hn[4][2];
  #pragma unroll
  for (int rr = 0; rr < 4; ++rr) {
    const int r = rg * 4 + rr;
    float c0 = xh[r * 384 + 256 + j0], c1 = xh[r * 384 + 256 + j0 + 1];
    float i0 = acc[rr][0][0] + bi[0][0], i1 = acc[rr][0][1] + bi[0][1];
    float f0 = acc[rr][1][0] + bi[1][0], f1 = acc[rr][1][1] + bi[1][1];
    float g0 = acc[rr][2][0] + bi[2][0], g1 = acc[rr][2][1] + bi[2][1];
    float o0 = acc[rr][3][0] + bi[3][0], o1 = acc[rr][3][1] + bi[3][1];
    float cn0 = sigm(f0) * c0 + sigm(i0) * tanh_(g0);
    float cn1 = sigm(f1) * c1 + sigm(i1) * tanh_(g1);
    hn[rr][0] = sigm(o0) * tanh_(cn0);
    hn[rr][1] = sigm(o1) * tanh_(cn1);
    *(float2*)(hL   + (size_t)(rowBase + r) * DD + j0) = make_float2(cn0, cn1);
    *(float2*)(Lbuf + (size_t)(rowBase + r) * DD + j0) = make_float2(hn[rr][0], hn[rr][1]);
  }
  __syncthreads();
  #pragma unroll
  for (int rr = 0; rr < 4; ++rr)
    *(float2*)(xh + (rg * 4 + rr) * 384 + j0) = make_float2(hn[rr][0], hn[rr][1]);
  __syncthreads();

  float a2[4][2];
  #pragma unroll
  for (int rr = 0; rr < 4; ++rr) { a2[rr][0] = 0.f; a2[rr][1] = 0.f; }
  #pragma unroll 2
  for (int k = 0; k < 128; ++k) {
    const float2 w = *(const float2*)(Wlct + k * 128 + j0);
    #pragma unroll
    for (int rr = 0; rr < 4; ++rr) {
      float x = xh[(rg * 4 + rr) * 384 + k];
      a2[rr][0] = fmaf(x, w.x, a2[rr][0]);
      a2[rr][1] = fmaf(x, w.y, a2[rr][1]);
    }
  }
  float b0 = blc[j0], b1 = blc[j0 + 1];
  #pragma unroll
  for (int rr = 0; rr < 4; ++rr)
    *(float2*)(LCp + (size_t)(rowBase + rg * 4 + rr) * DD + j0) = make_float2(a2[rr][0] + b0, a2[rr][1] + b1);
}

// ---------------- launch ----------------

extern "C" void kernel_launch(void* const* d_in, const int* in_sizes, int n_in,
                              void* d_out, int out_size, void* d_ws, size_t ws_size,
                              hipStream_t stream) {
  const float* L0   = (const float*)d_in[0];
  // d_in[1] = C_state (unused by reference), d_in[5] = n_vars (flip is identity)
  const float* hL0  = (const float*)d_in[2];
  const float* hC0  = (const float*)d_in[3];
  const float* M    = (const float*)d_in[4];
  const float* Wlc  = (const float*)d_in[6];
  const float* blc  = (const float*)d_in[7];
  const float* Wcl  = (const float*)d_in[8];
  const float* bcl  = (const float*)d_in[9];
  const float* WihC = (const float*)d_in[10];
  const float* WhhC = (const float*)d_in[11];
  const float* bihC = (const float*)d_in[12];
  const float* bhhC = (const float*)d_in[13];
  const float* WihL = (const float*)d_in[14];
  const float* WhhL = (const float*)d_in[15];
  const float* bihL = (const float*)d_in[16];
  const float* bhhL = (const float*)d_in[17];

  float* ws   = (float*)d_ws;
  float* hL   = ws;                       // NL*D
  float* hC   = hL   + NL * DD;           // NC*D
  float* LCp  = hC   + NC * DD;           // NL*D
  float* CLp  = LCp  + NL * DD;           // NC*D
  float* WCt  = CLp  + NC * DD;           // 256*512
  float* WLt  = WCt  + 256 * 512;         // 384*512
  float* Wlct = WLt  + 384 * 512;         // 128*128
  float* Wclt = Wlct + 128 * 128;         // 128*128
  int*   csr  = (int*)(Wclt + 128 * 128); // NL*ROWW
  int*   csc  = csr  + NL * ROWW;         // NC*COLW
  int*   rcnt = csc  + NC * COLW;         // NL
  int*   ccnt = rcnt + NL;                // NC  (contiguous with rcnt)
  float* Lbuf = (float*)d_out;            // L lives in d_out the whole time

  hipMemsetAsync(rcnt, 0, (NL + NC) * sizeof(int), stream);

  copy_f4<<<1024, 256, 0, stream>>>((float4*)Lbuf, (const float4*)L0,  NL * DD / 4);
  copy_f4<<<1024, 256, 0, stream>>>((float4*)hL,   (const float4*)hL0, NL * DD / 4);
  copy_f4<<<1024, 256, 0, stream>>>((float4*)hC,   (const float4*)hC0, NC * DD / 4);

  transpose_into<<<(512 * 128 + 255) / 256, 256, 0, stream>>>(WCt,             WihC, 512, 128);
  transpose_into<<<(512 * 128 + 255) / 256, 256, 0, stream>>>(WCt + 128 * 512, WhhC, 512, 128);
  transpose_into<<<(512 * 256 + 255) / 256, 256, 0, stream>>>(WLt,             WihL, 512, 256);
  transpose_into<<<(512 * 128 + 255) / 256, 256, 0, stream>>>(WLt + 256 * 512, WhhL, 512, 128);
  transpose_into<<<(128 * 128 + 255) / 256, 256, 0, stream>>>(Wlct, Wlc, 128, 128);
  transpose_into<<<(128 * 128 + 255) / 256, 256, 0, stream>>>(Wclt, Wcl, 128, 128);

  scan_M<<<4096, 256, 0, stream>>>((const float4*)M, csr, csc, rcnt, ccnt);

  gemm128<<<NL / 32, 256, 0, stream>>>(Lbuf, Wlct, blc, LCp);  // initial LC_pre

  for (int t = 0; t < TSTEPS; ++t) {
    clause_step<<<NC / 32, 256, 0, stream>>>(LCp, csc, ccnt, WCt, bihC, bhhC, Wclt, bcl, hC, CLp);
    literal_step<<<NL / 16, 256, 0, stream>>>(CLp, csr, rcnt, WLt, bihL, bhhL, Wlct, blc, hL, Lbuf, LCp);
  }
}

// Round 2
// 3682.960 us; speedup vs baseline: 1.2030x; 1.2030x over previous
//
#include <hip/hip_runtime.h>
#include <math.h>

#define DD   128
#define NV   4000
#define NL   8000
#define NC   16000
#define TSTEPS 8
#define ROWW 96    // max clauses per literal (mean 40, std 6.3 -> huge margin)
#define COLW 64    // max literals per clause (mean 20, std 4.4 -> huge margin)
#define CROWS 16   // clause rows per block
#define LROWS 8    // literal rows per block

__device__ __forceinline__ float frcp(float x) {
#if __has_builtin(__builtin_amdgcn_rcpf)
  return __builtin_amdgcn_rcpf(x);
#else
  return 1.f / x;
#endif
}
__device__ __forceinline__ float sigm(float x) {
  return frcp(1.f + __expf(-x));
}
__device__ __forceinline__ float tanh_(float x) {
  float e = __expf(2.f * x);
  return 1.f - 2.f * frcp(e + 1.f);
}
__device__ __forceinline__ void add4(float4& a, const float4 b) {
  a.x += b.x; a.y += b.y; a.z += b.z; a.w += b.w;
}

// ---------------- preprocessing kernels ----------------

__global__ __launch_bounds__(256) void copy_f4(float4* __restrict__ dst, const float4* __restrict__ src, int n4) {
  int stride = gridDim.x * blockDim.x;
  for (int i = blockIdx.x * blockDim.x + threadIdx.x; i < n4; i += stride) dst[i] = src[i];
}

// dst[k*J + j] = src[j*K + k]
__global__ __launch_bounds__(256) void transpose_into(float* __restrict__ dst, const float* __restrict__ src, int J, int K) {
  int i = blockIdx.x * blockDim.x + threadIdx.x;
  if (i >= J * K) return;
  int j = i / K, k = i - j * K;
  dst[k * J + j] = src[i];
}

// one pass over M (512 MB): build padded-ELL both directions
__global__ __launch_bounds__(256) void scan_M(const float4* __restrict__ M4,
                                              int* __restrict__ csr, int* __restrict__ csc,
                                              int* __restrict__ rcnt, int* __restrict__ ccnt) {
  const int total = (NL * NC) / 4;  // 32M float4
  int stride = gridDim.x * blockDim.x;
  for (int i = blockIdx.x * blockDim.x + threadIdx.x; i < total; i += stride) {
    float4 v = M4[i];
    if (v.x == 0.f && v.y == 0.f && v.z == 0.f && v.w == 0.f) continue;
    int base = i * 4;              // NC % 4 == 0 -> all 4 elems share the row
    int l = base / NC;
    int c0 = base - l * NC;
    float vv[4] = {v.x, v.y, v.z, v.w};
    #pragma unroll
    for (int e = 0; e < 4; ++e) {
      if (vv[e] != 0.f) {
        int c = c0 + e;
        int rp = atomicAdd(&rcnt[l], 1);
        if (rp < ROWW) csr[l * ROWW + rp] = c;
        int cp = atomicAdd(&ccnt[c], 1);
        if (cp < COLW) csc[c * COLW + cp] = l;
      }
    }
  }
}

// Y(rows x 128) = X(rows x 128) @ Wt(128x128, Wt[k][j]) + b
__global__ __launch_bounds__(256) void gemm128(const float* __restrict__ X, const float* __restrict__ Wt,
                                               const float* __restrict__ b, float* __restrict__ Y) {
  __shared__ float xs[16 * 128];
  const int t = threadIdx.x;
  const int rowBase = blockIdx.x * 16;
  for (int ii = t; ii < 16 * 32; ii += 256)
    ((float4*)xs)[ii] = ((const float4*)(X + (size_t)rowBase * DD))[ii];
  __syncthreads();
  const int jg = t & 31, rg = t >> 5;   // 8 row-groups x 2 rows ; 32 j-groups x 4 cols
  const int j0 = jg * 4;
  float acc[2][4];
  #pragma unroll
  for (int rr = 0; rr < 2; ++rr)
    #pragma unroll
    for (int e = 0; e < 4; ++e) acc[rr][e] = 0.f;
  #pragma unroll 4
  for (int k = 0; k < 128; ++k) {
    const float4 w = *(const float4*)(Wt + k * 128 + j0);
    float x0 = xs[(rg * 2 + 0) * 128 + k];
    float x1 = xs[(rg * 2 + 1) * 128 + k];
    acc[0][0] = fmaf(x0, w.x, acc[0][0]); acc[0][1] = fmaf(x0, w.y, acc[0][1]);
    acc[0][2] = fmaf(x0, w.z, acc[0][2]); acc[0][3] = fmaf(x0, w.w, acc[0][3]);
    acc[1][0] = fmaf(x1, w.x, acc[1][0]); acc[1][1] = fmaf(x1, w.y, acc[1][1]);
    acc[1][2] = fmaf(x1, w.z, acc[1][2]); acc[1][3] = fmaf(x1, w.w, acc[1][3]);
  }
  const float4 bv = *(const float4*)(b + j0);
  #pragma unroll
  for (int rr = 0; rr < 2; ++rr) {
    float4 o = make_float4(acc[rr][0] + bv.x, acc[rr][1] + bv.y, acc[rr][2] + bv.z, acc[rr][3] + bv.w);
    *(float4*)(Y + (size_t)(rowBase + rg * 2 + rr) * DD + j0) = o;
  }
}

// ---------------- per-step fused kernels ----------------
// clause update: x = gather(LC_pre), gates = [x|hC] @ WCt + b, LSTM (h=c=hC),
// hC <- c_new, CL_pre <- h_new @ Wcl^T + bcl
__global__ __launch_bounds__(256, 4) void clause_step(
    const float* __restrict__ LCp, const int* __restrict__ csc, const int* __restrict__ ccnt,
    const float* __restrict__ WCt, const float* __restrict__ bih, const float* __restrict__ bhh,
    const float* __restrict__ Wclt, const float* __restrict__ bcl,
    float* __restrict__ hC, float* __restrict__ CLp) {
  __shared__ float xh[CROWS * 256];   // [row][0:128)=x msgs, [128:256)=hC(=c_old)
  const int t = threadIdx.x;
  const int rowBase = blockIdx.x * CROWS;

  { // gather: 16 threads/row, 8 cols (2 float4) each
    const int r = t >> 4, cg = t & 15;
    const int c = rowBase + r;
    int cnt = ccnt[c]; if (cnt > COLW) cnt = COLW;
    const int* lst = csc + c * COLW;
    float4 a0 = make_float4(0,0,0,0), a1 = a0;
    for (int j = 0; j < cnt; ++j) {
      const float4* s = (const float4*)(LCp + (size_t)lst[j] * DD) + (cg << 1);
      add4(a0, s[0]); add4(a1, s[1]);
    }
    float4* dst = (float4*)(xh + r * 256) + (cg << 1);
    dst[0] = a0; dst[1] = a1;
  }
  for (int ii = t; ii < CROWS * 32; ii += 256) {  // stage hC rows
    int r = ii >> 5, q = ii & 31;
    ((float4*)(xh + r * 256 + 128))[q] = ((const float4*)(hC + (size_t)(rowBase + r) * DD))[q];
  }
  __syncthreads();

  const int jg = t & 31, rg = t >> 5;  // 32 j-groups x 4 cols ; 8 row-groups x 2 rows
  const int j0 = jg * 4;
  float acc[2][4][4];                  // [row][gate][col] = 32 accumulators
  #pragma unroll
  for (int rr = 0; rr < 2; ++rr)
    #pragma unroll
    for (int gt = 0; gt < 4; ++gt)
      #pragma unroll
      for (int e = 0; e < 4; ++e) acc[rr][gt][e] = 0.f;

  #pragma unroll 2
  for (int k = 0; k < 256; ++k) {
    float x0 = xh[(rg * 2 + 0) * 256 + k];
    float x1 = xh[(rg * 2 + 1) * 256 + k];
    #pragma unroll
    for (int gt = 0; gt < 4; ++gt) {
      const float4 w = *(const float4*)(WCt + k * 512 + gt * 128 + j0);
      acc[0][gt][0] = fmaf(x0, w.x, acc[0][gt][0]); acc[0][gt][1] = fmaf(x0, w.y, acc[0][gt][1]);
      acc[0][gt][2] = fmaf(x0, w.z, acc[0][gt][2]); acc[0][gt][3] = fmaf(x0, w.w, acc[0][gt][3]);
      acc[1][gt][0] = fmaf(x1, w.x, acc[1][gt][0]); acc[1][gt][1] = fmaf(x1, w.y, acc[1][gt][1]);
      acc[1][gt][2] = fmaf(x1, w.z, acc[1][gt][2]); acc[1][gt][3] = fmaf(x1, w.w, acc[1][gt][3]);
    }
  }

  float bs[4][4];
  #pragma unroll
  for (int gt = 0; gt < 4; ++gt)
    #pragma unroll
    for (int e = 0; e < 4; ++e)
      bs[gt][e] = bih[gt * 128 + j0 + e] + bhh[gt * 128 + j0 + e];

  float hn[2][4];
  #pragma unroll
  for (int rr = 0; rr < 2; ++rr) {
    const int r = rg * 2 + rr;
    const float4 cold = *(const float4*)(xh + r * 256 + 128 + j0);
    float co[4] = {cold.x, cold.y, cold.z, cold.w};
    float cn[4];
    #pragma unroll
    for (int e = 0; e < 4; ++e) {
      float iv = acc[rr][0][e] + bs[0][e];
      float fv = acc[rr][1][e] + bs[1][e];
      float gv = acc[rr][2][e] + bs[2][e];
      float ov = acc[rr][3][e] + bs[3][e];
      cn[e] = sigm(fv) * co[e] + sigm(iv) * tanh_(gv);
      hn[rr][e] = sigm(ov) * tanh_(cn[e]);
    }
    *(float4*)(hC + (size_t)(rowBase + r) * DD + j0) = make_float4(cn[0], cn[1], cn[2], cn[3]);
  }
  __syncthreads();   // everyone done reading msg region
  #pragma unroll
  for (int rr = 0; rr < 2; ++rr)
    *(float4*)(xh + (rg * 2 + rr) * 256 + j0) = make_float4(hn[rr][0], hn[rr][1], hn[rr][2], hn[rr][3]);
  __syncthreads();

  float a2[2][4];
  #pragma unroll
  for (int rr = 0; rr < 2; ++rr)
    #pragma unroll
    for (int e = 0; e < 4; ++e) a2[rr][e] = 0.f;
  #pragma unroll 4
  for (int k = 0; k < 128; ++k) {
    const float4 w = *(const float4*)(Wclt + k * 128 + j0);
    float x0 = xh[(rg * 2 + 0) * 256 + k];
    float x1 = xh[(rg * 2 + 1) * 256 + k];
    a2[0][0] = fmaf(x0, w.x, a2[0][0]); a2[0][1] = fmaf(x0, w.y, a2[0][1]);
    a2[0][2] = fmaf(x0, w.z, a2[0][2]); a2[0][3] = fmaf(x0, w.w, a2[0][3]);
    a2[1][0] = fmaf(x1, w.x, a2[1][0]); a2[1][1] = fmaf(x1, w.y, a2[1][1]);
    a2[1][2] = fmaf(x1, w.z, a2[1][2]); a2[1][3] = fmaf(x1, w.w, a2[1][3]);
  }
  const float4 bv = *(const float4*)(bcl + j0);
  #pragma unroll
  for (int rr = 0; rr < 2; ++rr) {
    float4 o = make_float4(a2[rr][0] + bv.x, a2[rr][1] + bv.y, a2[rr][2] + bv.z, a2[rr][3] + bv.w);
    *(float4*)(CLp + (size_t)(rowBase + rg * 2 + rr) * DD + j0) = o;
  }
}

// literal update: msg = gather(CL_pre); inp=[msg|L]; gates = [inp|hL] @ WLt + b (K=384),
// LSTM (h=c=hL); L <- h_new (in d_out), hL <- c_new, LC_pre <- h_new @ Wlc^T + blc
__global__ __launch_bounds__(256, 4) void literal_step(
    const float* __restrict__ CLp, const int* __restrict__ csr, const int* __restrict__ rcnt,
    const float* __restrict__ WLt, const float* __restrict__ bih, const float* __restrict__ bhh,
    const float* __restrict__ Wlct, const float* __restrict__ blc,
    float* __restrict__ hL, float* __restrict__ Lbuf, float* __restrict__ LCp) {
  __shared__ float xh[LROWS * 384];  // [row][0:128)=msg, [128:256)=L, [256:384)=hL(=c_old)
  const int t = threadIdx.x;
  const int rowBase = blockIdx.x * LROWS;

  { // gather: 32 threads/row, 4 cols (1 float4) each
    const int r = t >> 5, cg = t & 31;
    const int l = rowBase + r;
    int cnt = rcnt[l]; if (cnt > ROWW) cnt = ROWW;
    const int* lst = csr + l * ROWW;
    float4 a0 = make_float4(0,0,0,0);
    for (int j = 0; j < cnt; ++j)
      add4(a0, ((const float4*)(CLp + (size_t)lst[j] * DD))[cg]);
    ((float4*)(xh + r * 384))[cg] = a0;
  }
  for (int ii = t; ii < LROWS * 64; ii += 256) {  // stage L | hL
    int r = ii >> 6, q = ii & 63;
    float4 v;
    if (q < 32) v = ((const float4*)(Lbuf + (size_t)(rowBase + r) * DD))[q];
    else        v = ((const float4*)(hL   + (size_t)(rowBase + r) * DD))[q - 32];
    ((float4*)(xh + r * 384 + 128))[q] = v;
  }
  __syncthreads();

  const int jg = t & 31, rg = t >> 5;   // 32 j-groups x 4 cols ; 8 rows, 1 row/thread
  const int j0 = jg * 4;
  float acc[4][4];                      // [gate][col] = 16 accumulators
  #pragma unroll
  for (int gt = 0; gt < 4; ++gt)
    #pragma unroll
    for (int e = 0; e < 4; ++e) acc[gt][e] = 0.f;

  #pragma unroll 2
  for (int k = 0; k < 384; ++k) {
    float x = xh[rg * 384 + k];
    #pragma unroll
    for (int gt = 0; gt < 4; ++gt) {
      const float4 w = *(const float4*)(WLt + k * 512 + gt * 128 + j0);
      acc[gt][0] = fmaf(x, w.x, acc[gt][0]); acc[gt][1] = fmaf(x, w.y, acc[gt][1]);
      acc[gt][2] = fmaf(x, w.z, acc[gt][2]); acc[gt][3] = fmaf(x, w.w, acc[gt][3]);
    }
  }

  float hn[4];
  {
    const float4 cold = *(const float4*)(xh + rg * 384 + 256 + j0);
    float co[4] = {cold.x, cold.y, cold.z, cold.w};
    float cn[4];
    #pragma unroll
    for (int e = 0; e < 4; ++e) {
      float iv = acc[0][e] + bih[0 * 128 + j0 + e] + bhh[0 * 128 + j0 + e];
      float fv = acc[1][e] + bih[1 * 128 + j0 + e] + bhh[1 * 128 + j0 + e];
      float gv = acc[2][e] + bih[2 * 128 + j0 + e] + bhh[2 * 128 + j0 + e];
      float ov = acc[3][e] + bih[3 * 128 + j0 + e] + bhh[3 * 128 + j0 + e];
      cn[e] = sigm(fv) * co[e] + sigm(iv) * tanh_(gv);
      hn[e] = sigm(ov) * tanh_(cn[e]);
    }
    *(float4*)(hL   + (size_t)(rowBase + rg) * DD + j0) = make_float4(cn[0], cn[1], cn[2], cn[3]);
    *(float4*)(Lbuf + (size_t)(rowBase + rg) * DD + j0) = make_float4(hn[0], hn[1], hn[2], hn[3]);
  }
  __syncthreads();   // everyone done reading msg region
  *(float4*)(xh + rg * 384 + j0) = make_float4(hn[0], hn[1], hn[2], hn[3]);
  __syncthreads();

  float a2[4] = {0.f, 0.f, 0.f, 0.f};
  #pragma unroll 4
  for (int k = 0; k < 128; ++k) {
    const float4 w = *(const float4*)(Wlct + k * 128 + j0);
    float x = xh[rg * 384 + k];
    a2[0] = fmaf(x, w.x, a2[0]); a2[1] = fmaf(x, w.y, a2[1]);
    a2[2] = fmaf(x, w.z, a2[2]); a2[3] = fmaf(x, w.w, a2[3]);
  }
  const float4 bv = *(const float4*)(blc + j0);
  *(float4*)(LCp + (size_t)(rowBase + rg) * DD + j0) =
      make_float4(a2[0] + bv.x, a2[1] + bv.y, a2[2] + bv.z, a2[3] + bv.w);
}

// ---------------- launch ----------------

extern "C" void kernel_launch(void* const* d_in, const int* in_sizes, int n_in,
                              void* d_out, int out_size, void* d_ws, size_t ws_size,
                              hipStream_t stream) {
  const float* L0   = (const float*)d_in[0];
  // d_in[1] = C_state (unused by reference), d_in[5] = n_vars (flip is identity)
  const float* hL0  = (const float*)d_in[2];
  const float* hC0  = (const float*)d_in[3];
  const float* M    = (const float*)d_in[4];
  const float* Wlc  = (const float*)d_in[6];
  const float* blc  = (const float*)d_in[7];
  const float* Wcl  = (const float*)d_in[8];
  const float* bcl  = (const float*)d_in[9];
  const float* WihC = (const float*)d_in[10];
  const float* WhhC = (const float*)d_in[11];
  const float* bihC = (const float*)d_in[12];
  const float* bhhC = (const float*)d_in[13];
  const float* WihL = (const float*)d_in[14];
  const float* WhhL = (const float*)d_in[15];
  const float* bihL = (const float*)d_in[16];
  const float* bhhL = (const float*)d_in[17];

  float* ws   = (float*)d_ws;
  float* hL   = ws;                       // NL*D
  float* hC   = hL   + NL * DD;           // NC*D
  float* LCp  = hC   + NC * DD;           // NL*D
  float* CLp  = LCp  + NL * DD;           // NC*D
  float* WCt  = CLp  + NC * DD;           // 256*512
  float* WLt  = WCt  + 256 * 512;         // 384*512
  float* Wlct = WLt  + 384 * 512;         // 128*128
  float* Wclt = Wlct + 128 * 128;         // 128*128
  int*   csr  = (int*)(Wclt + 128 * 128); // NL*ROWW
  int*   csc  = csr  + NL * ROWW;         // NC*COLW
  int*   rcnt = csc  + NC * COLW;         // NL
  int*   ccnt = rcnt + NL;                // NC  (contiguous with rcnt)
  float* Lbuf = (float*)d_out;            // L lives in d_out the whole time

  hipMemsetAsync(rcnt, 0, (NL + NC) * sizeof(int), stream);

  copy_f4<<<1024, 256, 0, stream>>>((float4*)Lbuf, (const float4*)L0,  NL * DD / 4);
  copy_f4<<<1024, 256, 0, stream>>>((float4*)hL,   (const float4*)hL0, NL * DD / 4);
  copy_f4<<<1024, 256, 0, stream>>>((float4*)hC,   (const float4*)hC0, NC * DD / 4);

  transpose_into<<<(512 * 128 + 255) / 256, 256, 0, stream>>>(WCt,             WihC, 512, 128);
  transpose_into<<<(512 * 128 + 255) / 256, 256, 0, stream>>>(WCt + 128 * 512, WhhC, 512, 128);
  transpose_into<<<(512 * 256 + 255) / 256, 256, 0, stream>>>(WLt,             WihL, 512, 256);
  transpose_into<<<(512 * 128 + 255) / 256, 256, 0, stream>>>(WLt + 256 * 512, WhhL, 512, 128);
  transpose_into<<<(128 * 128 + 255) / 256, 256, 0, stream>>>(Wlct, Wlc, 128, 128);
  transpose_into<<<(128 * 128 + 255) / 256, 256, 0, stream>>>(Wclt, Wcl, 128, 128);

  scan_M<<<4096, 256, 0, stream>>>((const float4*)M, csr, csc, rcnt, ccnt);

  gemm128<<<NL / 16, 256, 0, stream>>>(Lbuf, Wlct, blc, LCp);  // initial LC_pre

  for (int t = 0; t < TSTEPS; ++t) {
    clause_step<<<NC / CROWS, 256, 0, stream>>>(LCp, csc, ccnt, WCt, bihC, bhhC, Wclt, bcl, hC, CLp);
    literal_step<<<NL / LROWS, 256, 0, stream>>>(CLp, csr, rcnt, WLt, bihL, bhhL, Wlct, blc, hL, Lbuf, LCp);
  }
}

// Round 4
// 1485.878 us; speedup vs baseline: 2.9819x; 2.4786x over previous
//
#include <hip/hip_runtime.h>

#define DD   128
#define NL   8000
#define NC   16000
#define TSTEPS 8
#define ROWW 96    // max clauses per literal (mean 40, std 6.3)
#define COLW 64    // max literals per clause (mean 20, std 4.4)
#define OS   33    // LDS oct stride in short8 units (32 rows + 1 pad: kills staging bank conflicts)
#define SPLITS8 (32 * OS)        // short8s per split = 1056
#define SPLIT   (SPLITS8 * 8)    // shorts per split = 8448

typedef __attribute__((ext_vector_type(8))) short short8;
typedef __attribute__((ext_vector_type(4))) float f32x4;

__device__ __forceinline__ float frcp(float x) { return __builtin_amdgcn_rcpf(x); }
__device__ __forceinline__ float sigm(float x) { return frcp(1.f + __expf(-x)); }
__device__ __forceinline__ float tanh_(float x) {
  float e = __expf(2.f * x);
  return 1.f - 2.f * frcp(e + 1.f);
}
__device__ __forceinline__ void add4(float4& a, const float4 b) {
  a.x += b.x; a.y += b.y; a.z += b.z; a.w += b.w;
}
__device__ __forceinline__ unsigned short bfround(float v) {  // RNE fp32 -> bf16
  unsigned u = __float_as_uint(v);
  return (unsigned short)((u + 0x7FFF + ((u >> 16) & 1)) >> 16);
}
__device__ __forceinline__ float bf2f(unsigned short b) {
  return __uint_as_float(((unsigned)b) << 16);
}
__device__ __forceinline__ int4 packi4(const unsigned short* p) {
  return make_int4(p[0] | ((int)p[1] << 16), p[2] | ((int)p[3] << 16),
                   p[4] | ((int)p[5] << 16), p[6] | ((int)p[7] << 16));
}

// triple-split 8 floats -> 3 bf16 octets in LDS frag layout [oct(stride OS)][m][8]
__device__ __forceinline__ void store_oct3(unsigned short* A, int oct, int m,
                                           float4 a, float4 b) {
  float f[8] = {a.x, a.y, a.z, a.w, b.x, b.y, b.z, b.w};
  unsigned short h[8], md[8], lo[8];
  #pragma unroll
  for (int j = 0; j < 8; ++j) {
    h[j] = bfround(f[j]);
    float r1 = f[j] - bf2f(h[j]);       // exact (Sterbenz)
    md[j] = bfround(r1);
    float r2 = r1 - bf2f(md[j]);        // exact
    lo[j] = bfround(r2);
  }
  int base = (oct * OS + m) * 8;
  *(int4*)(A + base)             = packi4(h);
  *(int4*)(A + SPLIT + base)     = packi4(md);
  *(int4*)(A + 2 * SPLIT + base) = packi4(lo);
}

// ---------------- preprocessing ----------------

__global__ __launch_bounds__(256) void copy_f4(float4* __restrict__ dst, const float4* __restrict__ src, int n4) {
  int stride = gridDim.x * blockDim.x;
  for (int i = blockIdx.x * blockDim.x + threadIdx.x; i < n4; i += stride) dst[i] = src[i];
}

// one pass over M (512 MB): padded-ELL both directions
__global__ __launch_bounds__(256) void scan_M(const float4* __restrict__ M4,
                                              int* __restrict__ csr, int* __restrict__ csc,
                                              int* __restrict__ rcnt, int* __restrict__ ccnt) {
  const int total = (NL * NC) / 4;
  int stride = gridDim.x * blockDim.x;
  for (int i = blockIdx.x * blockDim.x + threadIdx.x; i < total; i += stride) {
    float4 v = M4[i];
    if (v.x == 0.f && v.y == 0.f && v.z == 0.f && v.w == 0.f) continue;
    int base = i * 4;
    int l = base / NC;
    int c0 = base - l * NC;
    float vv[4] = {v.x, v.y, v.z, v.w};
    #pragma unroll
    for (int e = 0; e < 4; ++e) {
      if (vv[e] != 0.f) {
        int c = c0 + e;
        int rp = atomicAdd(&rcnt[l], 1);
        if (rp < ROWW) csr[l * ROWW + rp] = c;
        int cp = atomicAdd(&ccnt[c], 1);
        if (cp < COLW) csc[c * COLW + cp] = l;
      }
    }
  }
}

__device__ __forceinline__ void split_store(float w, int idx, unsigned short* hi,
                                            unsigned short* md, unsigned short* lo) {
  unsigned short h = bfround(w);
  float r1 = w - bf2f(h);
  unsigned short m = bfround(r1);
  float r2 = r1 - bf2f(m);
  hi[idx] = h; md[idx] = m; lo[idx] = bfround(r2);
}

// combined clause weights B[k][n]: k<128: sum_d WihC[n,d]*Wlc[d,k]; k>=128: WhhC[n,k-128]
// packed octet layout: pk[((k/8)*512 + n)*8 + k%8], triple-split bf16
__global__ __launch_bounds__(256) void build_packC(
    const float* __restrict__ WihC, const float* __restrict__ Wlc, const float* __restrict__ WhhC,
    unsigned short* __restrict__ pkhi, unsigned short* __restrict__ pkmd, unsigned short* __restrict__ pklo) {
  int i = blockIdx.x * 256 + threadIdx.x;   // [0, 256*512)
  int k = i >> 9, n = i & 511;
  float w;
  if (k < 128) {
    float s = 0.f;
    for (int d = 0; d < 128; ++d) s += WihC[n * 128 + d] * Wlc[d * 128 + k];
    w = s;
  } else {
    w = WhhC[n * 128 + (k - 128)];
  }
  split_store(w, ((k >> 3) * 512 + n) * 8 + (k & 7), pkhi, pkmd, pklo);
}

// literal B[k][n]: k<128: sum_d WihL[n,d]*Wcl[d,k]; 128..255: WihL[n,k]; 256..383: WhhL[n,k-256]
__global__ __launch_bounds__(256) void build_packL(
    const float* __restrict__ WihL, const float* __restrict__ Wcl, const float* __restrict__ WhhL,
    unsigned short* __restrict__ pkhi, unsigned short* __restrict__ pkmd, unsigned short* __restrict__ pklo) {
  int i = blockIdx.x * 256 + threadIdx.x;   // [0, 384*512)
  int k = i >> 9, n = i & 511;
  float w;
  if (k < 128) {
    float s = 0.f;
    for (int d = 0; d < 128; ++d) s += WihL[n * 256 + d] * Wcl[d * 128 + k];
    w = s;
  } else if (k < 256) {
    w = WihL[n * 256 + k];
  } else {
    w = WhhL[n * 128 + (k - 256)];
  }
  split_store(w, ((k >> 3) * 512 + n) * 8 + (k & 7), pkhi, pkmd, pklo);
}

__global__ __launch_bounds__(256) void build_bias(
    const float* __restrict__ bihC, const float* __restrict__ bhhC,
    const float* __restrict__ WihC, const float* __restrict__ blc,
    const float* __restrict__ bihL, const float* __restrict__ bhhL,
    const float* __restrict__ WihL, const float* __restrict__ bcl,
    float* __restrict__ bsumC, float* __restrict__ bvecC,
    float* __restrict__ bsumL, float* __restrict__ bvecL) {
  int i = blockIdx.x * 256 + threadIdx.x;   // [0, 1024)
  if (i < 512) {
    bsumC[i] = bihC[i] + bhhC[i];
    float s = 0.f;
    for (int d = 0; d < 128; ++d) s += WihC[i * 128 + d] * blc[d];
    bvecC[i] = s;
  } else if (i < 1024) {
    int n = i - 512;
    bsumL[n] = bihL[n] + bhhL[n];
    float s = 0.f;
    for (int d = 0; d < 128; ++d) s += WihL[n * 256 + d] * bcl[d];
    bvecL[n] = s;
  }
}

// 6-term triple-split product: hh + hm + mh + hl + lh + mm  (error ~2^-27)
#define MFMA6(ACC, AH, AM, AL, BH, BM, BL)                                   \
  ACC = __builtin_amdgcn_mfma_f32_16x16x32_bf16(AH, BH, ACC, 0, 0, 0);       \
  ACC = __builtin_amdgcn_mfma_f32_16x16x32_bf16(AH, BM, ACC, 0, 0, 0);       \
  ACC = __builtin_amdgcn_mfma_f32_16x16x32_bf16(AM, BH, ACC, 0, 0, 0);       \
  ACC = __builtin_amdgcn_mfma_f32_16x16x32_bf16(AH, BL, ACC, 0, 0, 0);       \
  ACC = __builtin_amdgcn_mfma_f32_16x16x32_bf16(AL, BH, ACC, 0, 0, 0);       \
  ACC = __builtin_amdgcn_mfma_f32_16x16x32_bf16(AM, BM, ACC, 0, 0, 0);

// ---------------- fused MFMA step kernels ----------------
// Block: 32 rows, 512 threads (8 waves). Wave w owns output cols w*16..w*16+15 of all 4 gates.
// A (gather + states) in LDS as triple-split bf16 octets; B streams from L2.

__global__ __launch_bounds__(512, 4) void clause_mfma(
    const float* __restrict__ Lbuf, const int* __restrict__ csc, const int* __restrict__ ccnt,
    const unsigned short* __restrict__ pkhi, const unsigned short* __restrict__ pkmd,
    const unsigned short* __restrict__ pklo,
    const float* __restrict__ bsum, const float* __restrict__ bvec,
    float* __restrict__ hC, float* __restrict__ Cs) {
  __shared__ unsigned short A[3 * SPLIT];   // 50,688 B
  const int t = threadIdx.x;
  const int rowBase = blockIdx.x * 32;

  { // stage A: K = [msgs(128)=oct 0..15 | hC(128)=oct 16..31]
    const int r = t >> 4, sub = t & 15;
    const int c = rowBase + r;
    int cnt = ccnt[c]; int cl = cnt > COLW ? COLW : cnt;
    const int* lst = csc + c * COLW;
    float4 a0 = make_float4(0, 0, 0, 0), a1 = a0;
    for (int j = 0; j < cl; ++j) {
      const float4* s4 = (const float4*)(Lbuf + (size_t)lst[j] * DD + sub * 8);
      add4(a0, s4[0]); add4(a1, s4[1]);
    }
    store_oct3(A, sub, r, a0, a1);
    const float4* h4 = (const float4*)(hC + (size_t)c * DD + sub * 8);
    store_oct3(A, 16 + sub, r, h4[0], h4[1]);
  }
  __syncthreads();

  const int w = t >> 6, l = t & 63;
  const int quad = l >> 4, lane16 = l & 15;
  const int cw = w * 16 + lane16;   // output col 0..127
  f32x4 acc[2][4];
  #pragma unroll
  for (int mt = 0; mt < 2; ++mt)
    #pragma unroll
    for (int g = 0; g < 4; ++g) acc[mt][g] = (f32x4){0.f, 0.f, 0.f, 0.f};

  const short8* As = (const short8*)A;      // idx = oct*OS + m; splits at +SPLITS8
  const short8* Bh = (const short8*)pkhi;   // idx = oct*512 + n
  const short8* Bm = (const short8*)pkmd;
  const short8* Bl = (const short8*)pklo;

  #pragma unroll 1
  for (int s = 0; s < 8; ++s) {             // K=256
    int ao = (s * 4 + quad) * OS + lane16;
    short8 a0h = As[ao],                a1h = As[ao + 16];
    short8 a0m = As[SPLITS8 + ao],      a1m = As[SPLITS8 + ao + 16];
    short8 a0l = As[2 * SPLITS8 + ao],  a1l = As[2 * SPLITS8 + ao + 16];
    int bo = (s * 4 + quad) * 512 + cw;
    #pragma unroll
    for (int g = 0; g < 4; ++g) {
      short8 bh = Bh[bo + g * 128];
      short8 bm = Bm[bo + g * 128];
      short8 bl = Bl[bo + g * 128];
      MFMA6(acc[0][g], a0h, a0m, a0l, bh, bm, bl);
      MFMA6(acc[1][g], a1h, a1m, a1l, bh, bm, bl);
    }
  }

  float bs_[4], bv_[4];
  #pragma unroll
  for (int g = 0; g < 4; ++g) { bs_[g] = bsum[g * 128 + cw]; bv_[g] = bvec[g * 128 + cw]; }
  #pragma unroll
  for (int mt = 0; mt < 2; ++mt) {
    #pragma unroll
    for (int reg = 0; reg < 4; ++reg) {
      int row = rowBase + mt * 16 + quad * 4 + reg;
      float deg = (float)ccnt[row];
      float co = hC[(size_t)row * DD + cw];
      float iv = acc[mt][0][reg] + bs_[0] + deg * bv_[0];
      float fv = acc[mt][1][reg] + bs_[1] + deg * bv_[1];
      float gv = acc[mt][2][reg] + bs_[2] + deg * bv_[2];
      float ov = acc[mt][3][reg] + bs_[3] + deg * bv_[3];
      float cn = sigm(fv) * co + sigm(iv) * tanh_(gv);
      hC[(size_t)row * DD + cw] = cn;
      Cs[(size_t)row * DD + cw] = sigm(ov) * tanh_(cn);
    }
  }
}

__global__ __launch_bounds__(512, 4) void literal_mfma(
    const float* __restrict__ Cs, const int* __restrict__ csr, const int* __restrict__ rcnt,
    const unsigned short* __restrict__ pkhi, const unsigned short* __restrict__ pkmd,
    const unsigned short* __restrict__ pklo,
    const float* __restrict__ bsum, const float* __restrict__ bvec,
    float* __restrict__ hL, float* __restrict__ Lbuf) {
  __shared__ unsigned short A[3 * SPLIT];   // 50,688 B, two-phase K staging
  const int t = threadIdx.x;
  const int rowBase = blockIdx.x * 32;
  const int r = t >> 4, sub = t & 15;
  const int lr = rowBase + r;

  { // phase-1 stage: K 0..255 = [msgs(128)=oct 0..15 | L(128)=oct 16..31]
    int cnt = rcnt[lr]; int cl = cnt > ROWW ? ROWW : cnt;
    const int* lst = csr + lr * ROWW;
    float4 a0 = make_float4(0, 0, 0, 0), a1 = a0;
    for (int j = 0; j < cl; ++j) {
      const float4* s4 = (const float4*)(Cs + (size_t)lst[j] * DD + sub * 8);
      add4(a0, s4[0]); add4(a1, s4[1]);
    }
    store_oct3(A, sub, r, a0, a1);
    const float4* l4 = (const float4*)(Lbuf + (size_t)lr * DD + sub * 8);
    store_oct3(A, 16 + sub, r, l4[0], l4[1]);
  }
  __syncthreads();

  const int w = t >> 6, l = t & 63;
  const int quad = l >> 4, lane16 = l & 15;
  const int cw = w * 16 + lane16;
  f32x4 acc[2][4];
  #pragma unroll
  for (int mt = 0; mt < 2; ++mt)
    #pragma unroll
    for (int g = 0; g < 4; ++g) acc[mt][g] = (f32x4){0.f, 0.f, 0.f, 0.f};

  const short8* As = (const short8*)A;
  const short8* Bh = (const short8*)pkhi;
  const short8* Bm = (const short8*)pkmd;
  const short8* Bl = (const short8*)pklo;

  #pragma unroll 1
  for (int s = 0; s < 8; ++s) {             // K 0..255
    int ao = (s * 4 + quad) * OS + lane16;
    short8 a0h = As[ao],                a1h = As[ao + 16];
    short8 a0m = As[SPLITS8 + ao],      a1m = As[SPLITS8 + ao + 16];
    short8 a0l = As[2 * SPLITS8 + ao],  a1l = As[2 * SPLITS8 + ao + 16];
    int bo = (s * 4 + quad) * 512 + cw;
    #pragma unroll
    for (int g = 0; g < 4; ++g) {
      short8 bh = Bh[bo + g * 128];
      short8 bm = Bm[bo + g * 128];
      short8 bl = Bl[bo + g * 128];
      MFMA6(acc[0][g], a0h, a0m, a0l, bh, bm, bl);
      MFMA6(acc[1][g], a1h, a1m, a1l, bh, bm, bl);
    }
  }

  __syncthreads();   // all phase-1 LDS reads done
  { // phase-2 stage: hL -> octs 0..15 (reusing buffer)
    const float4* h4 = (const float4*)(hL + (size_t)lr * DD + sub * 8);
    store_oct3(A, sub, r, h4[0], h4[1]);
  }
  __syncthreads();

  #pragma unroll 1
  for (int s = 8; s < 12; ++s) {            // K 256..383 (hL)
    int ao = ((s - 8) * 4 + quad) * OS + lane16;
    short8 a0h = As[ao],                a1h = As[ao + 16];
    short8 a0m = As[SPLITS8 + ao],      a1m = As[SPLITS8 + ao + 16];
    short8 a0l = As[2 * SPLITS8 + ao],  a1l = As[2 * SPLITS8 + ao + 16];
    int bo = (s * 4 + quad) * 512 + cw;
    #pragma unroll
    for (int g = 0; g < 4; ++g) {
      short8 bh = Bh[bo + g * 128];
      short8 bm = Bm[bo + g * 128];
      short8 bl = Bl[bo + g * 128];
      MFMA6(acc[0][g], a0h, a0m, a0l, bh, bm, bl);
      MFMA6(acc[1][g], a1h, a1m, a1l, bh, bm, bl);
    }
  }

  float bs_[4], bv_[4];
  #pragma unroll
  for (int g = 0; g < 4; ++g) { bs_[g] = bsum[g * 128 + cw]; bv_[g] = bvec[g * 128 + cw]; }
  #pragma unroll
  for (int mt = 0; mt < 2; ++mt) {
    #pragma unroll
    for (int reg = 0; reg < 4; ++reg) {
      int row = rowBase + mt * 16 + quad * 4 + reg;
      float deg = (float)rcnt[row];
      float co = hL[(size_t)row * DD + cw];
      float iv = acc[mt][0][reg] + bs_[0] + deg * bv_[0];
      float fv = acc[mt][1][reg] + bs_[1] + deg * bv_[1];
      float gv = acc[mt][2][reg] + bs_[2] + deg * bv_[2];
      float ov = acc[mt][3][reg] + bs_[3] + deg * bv_[3];
      float cn = sigm(fv) * co + sigm(iv) * tanh_(gv);
      hL[(size_t)row * DD + cw] = cn;
      Lbuf[(size_t)row * DD + cw] = sigm(ov) * tanh_(cn);
    }
  }
}

// ---------------- launch ----------------

extern "C" void kernel_launch(void* const* d_in, const int* in_sizes, int n_in,
                              void* d_out, int out_size, void* d_ws, size_t ws_size,
                              hipStream_t stream) {
  const float* L0   = (const float*)d_in[0];
  // d_in[1] = C_state (unused), d_in[5] = n_vars (flip is identity)
  const float* hL0  = (const float*)d_in[2];
  const float* hC0  = (const float*)d_in[3];
  const float* M    = (const float*)d_in[4];
  const float* Wlc  = (const float*)d_in[6];
  const float* blc  = (const float*)d_in[7];
  const float* Wcl  = (const float*)d_in[8];
  const float* bcl  = (const float*)d_in[9];
  const float* WihC = (const float*)d_in[10];
  const float* WhhC = (const float*)d_in[11];
  const float* bihC = (const float*)d_in[12];
  const float* bhhC = (const float*)d_in[13];
  const float* WihL = (const float*)d_in[14];
  const float* WhhL = (const float*)d_in[15];
  const float* bihL = (const float*)d_in[16];
  const float* bhhL = (const float*)d_in[17];

  float* ws    = (float*)d_ws;
  float* hL    = ws;                         // NL*DD
  float* hC    = hL + NL * DD;               // NC*DD
  float* Cs    = hC + NC * DD;               // NC*DD
  float* bsumC = Cs + NC * DD;               // 512
  float* bvecC = bsumC + 512;
  float* bsumL = bvecC + 512;
  float* bvecL = bsumL + 512;
  unsigned short* pkChi = (unsigned short*)(bvecL + 512);   // 256*512 each
  unsigned short* pkCmd = pkChi + 256 * 512;
  unsigned short* pkClo = pkCmd + 256 * 512;
  unsigned short* pkLhi = pkClo + 256 * 512;                // 384*512 each
  unsigned short* pkLmd = pkLhi + 384 * 512;
  unsigned short* pkLlo = pkLmd + 384 * 512;
  int* csr  = (int*)(pkLlo + 384 * 512);     // NL*ROWW
  int* csc  = csr + NL * ROWW;               // NC*COLW
  int* rcnt = csc + NC * COLW;               // NL
  int* ccnt = rcnt + NL;                     // NC (contiguous with rcnt)
  float* Lbuf = (float*)d_out;               // literal state lives in d_out

  hipMemsetAsync(rcnt, 0, (NL + NC) * sizeof(int), stream);

  copy_f4<<<1024, 256, 0, stream>>>((float4*)Lbuf, (const float4*)L0,  NL * DD / 4);
  copy_f4<<<1024, 256, 0, stream>>>((float4*)hL,   (const float4*)hL0, NL * DD / 4);
  copy_f4<<<1024, 256, 0, stream>>>((float4*)hC,   (const float4*)hC0, NC * DD / 4);

  scan_M<<<4096, 256, 0, stream>>>((const float4*)M, csr, csc, rcnt, ccnt);

  build_packC<<<(256 * 512) / 256, 256, 0, stream>>>(WihC, Wlc, WhhC, pkChi, pkCmd, pkClo);
  build_packL<<<(384 * 512) / 256, 256, 0, stream>>>(WihL, Wcl, WhhL, pkLhi, pkLmd, pkLlo);
  build_bias<<<4, 256, 0, stream>>>(bihC, bhhC, WihC, blc, bihL, bhhL, WihL, bcl,
                                    bsumC, bvecC, bsumL, bvecL);

  for (int t = 0; t < TSTEPS; ++t) {
    clause_mfma<<<NC / 32, 512, 0, stream>>>(Lbuf, csc, ccnt, pkChi, pkCmd, pkClo,
                                             bsumC, bvecC, hC, Cs);
    literal_mfma<<<NL / 32, 512, 0, stream>>>(Cs, csr, rcnt, pkLhi, pkLmd, pkLlo,
                                              bsumL, bvecL, hL, Lbuf);
  }
}

// Round 5
// 1473.435 us; speedup vs baseline: 3.0071x; 1.0084x over previous
//
#include <hip/hip_runtime.h>

#define DD   128
#define NL   8000
#define NC   16000
#define TSTEPS 8
#define ROWW 96    // max clauses per literal (mean 40, std 6.3)
#define COLW 64    // max literals per clause (mean 20, std 4.4)
#define OS   33    // LDS oct stride in short8 units (32 rows + 1 pad)
#define SPLITS8 (32 * OS)        // short8s per split = 1056
#define SPLIT   (SPLITS8 * 8)    // shorts per split = 8448

typedef __attribute__((ext_vector_type(8))) short short8;
typedef __attribute__((ext_vector_type(4))) float f32x4;

__device__ __forceinline__ float frcp(float x) { return __builtin_amdgcn_rcpf(x); }
__device__ __forceinline__ float sigm(float x) { return frcp(1.f + __expf(-x)); }
__device__ __forceinline__ float tanh_(float x) {
  float e = __expf(2.f * x);
  return 1.f - 2.f * frcp(e + 1.f);
}
__device__ __forceinline__ void add4(float4& a, const float4 b) {
  a.x += b.x; a.y += b.y; a.z += b.z; a.w += b.w;
}
__device__ __forceinline__ unsigned short bfround(float v) {  // RNE fp32 -> bf16
  unsigned u = __float_as_uint(v);
  return (unsigned short)((u + 0x7FFF + ((u >> 16) & 1)) >> 16);
}
__device__ __forceinline__ float bf2f(unsigned short b) {
  return __uint_as_float(((unsigned)b) << 16);
}
__device__ __forceinline__ int4 packi4(const unsigned short* p) {
  return make_int4(p[0] | ((int)p[1] << 16), p[2] | ((int)p[3] << 16),
                   p[4] | ((int)p[5] << 16), p[6] | ((int)p[7] << 16));
}

// triple-split 8 floats -> 3 bf16 octets in LDS frag layout [oct(stride OS)][m][8]
__device__ __forceinline__ void store_oct3(unsigned short* A, int oct, int m,
                                           float4 a, float4 b) {
  float f[8] = {a.x, a.y, a.z, a.w, b.x, b.y, b.z, b.w};
  unsigned short h[8], md[8], lo[8];
  #pragma unroll
  for (int j = 0; j < 8; ++j) {
    h[j] = bfround(f[j]);
    float r1 = f[j] - bf2f(h[j]);       // exact (Sterbenz)
    md[j] = bfround(r1);
    float r2 = r1 - bf2f(md[j]);        // exact
    lo[j] = bfround(r2);
  }
  int base = (oct * OS + m) * 8;
  *(int4*)(A + base)             = packi4(h);
  *(int4*)(A + SPLIT + base)     = packi4(md);
  *(int4*)(A + 2 * SPLIT + base) = packi4(lo);
}

// ---------------- preprocessing ----------------

__global__ __launch_bounds__(256) void copy_f4(float4* __restrict__ dst, const float4* __restrict__ src, int n4) {
  int stride = gridDim.x * blockDim.x;
  for (int i = blockIdx.x * blockDim.x + threadIdx.x; i < n4; i += stride) dst[i] = src[i];
}

// one pass over M (512 MB): padded-ELL both directions
__global__ __launch_bounds__(256) void scan_M(const float4* __restrict__ M4,
                                              int* __restrict__ csr, int* __restrict__ csc,
                                              int* __restrict__ rcnt, int* __restrict__ ccnt) {
  const int total = (NL * NC) / 4;
  int stride = gridDim.x * blockDim.x;
  for (int i = blockIdx.x * blockDim.x + threadIdx.x; i < total; i += stride) {
    float4 v = M4[i];
    if (v.x == 0.f && v.y == 0.f && v.z == 0.f && v.w == 0.f) continue;
    int base = i * 4;
    int l = base / NC;
    int c0 = base - l * NC;
    float vv[4] = {v.x, v.y, v.z, v.w};
    #pragma unroll
    for (int e = 0; e < 4; ++e) {
      if (vv[e] != 0.f) {
        int c = c0 + e;
        int rp = atomicAdd(&rcnt[l], 1);
        if (rp < ROWW) csr[l * ROWW + rp] = c;
        int cp = atomicAdd(&ccnt[c], 1);
        if (cp < COLW) csc[c * COLW + cp] = l;
      }
    }
  }
}

__device__ __forceinline__ void split_store(float w, int idx, unsigned short* hi,
                                            unsigned short* md, unsigned short* lo) {
  unsigned short h = bfround(w);
  float r1 = w - bf2f(h);
  unsigned short m = bfround(r1);
  float r2 = r1 - bf2f(m);
  hi[idx] = h; md[idx] = m; lo[idx] = bfround(r2);
}

// combined clause weights B[k][n]: k<128: sum_d WihC[n,d]*Wlc[d,k]; k>=128: WhhC[n,k-128]
// packed octet layout: pk[((k/8)*512 + n)*8 + k%8], triple-split bf16
__global__ __launch_bounds__(256) void build_packC(
    const float* __restrict__ WihC, const float* __restrict__ Wlc, const float* __restrict__ WhhC,
    unsigned short* __restrict__ pkhi, unsigned short* __restrict__ pkmd, unsigned short* __restrict__ pklo) {
  int i = blockIdx.x * 256 + threadIdx.x;   // [0, 256*512)
  int k = i >> 9, n = i & 511;
  float w;
  if (k < 128) {
    float s = 0.f;
    for (int d = 0; d < 128; ++d) s += WihC[n * 128 + d] * Wlc[d * 128 + k];
    w = s;
  } else {
    w = WhhC[n * 128 + (k - 128)];
  }
  split_store(w, ((k >> 3) * 512 + n) * 8 + (k & 7), pkhi, pkmd, pklo);
}

// literal B[k][n]: k<128: sum_d WihL[n,d]*Wcl[d,k]; 128..255: WihL[n,k]; 256..383: WhhL[n,k-256]
__global__ __launch_bounds__(256) void build_packL(
    const float* __restrict__ WihL, const float* __restrict__ Wcl, const float* __restrict__ WhhL,
    unsigned short* __restrict__ pkhi, unsigned short* __restrict__ pkmd, unsigned short* __restrict__ pklo) {
  int i = blockIdx.x * 256 + threadIdx.x;   // [0, 384*512)
  int k = i >> 9, n = i & 511;
  float w;
  if (k < 128) {
    float s = 0.f;
    for (int d = 0; d < 128; ++d) s += WihL[n * 256 + d] * Wcl[d * 128 + k];
    w = s;
  } else if (k < 256) {
    w = WihL[n * 256 + k];
  } else {
    w = WhhL[n * 128 + (k - 256)];
  }
  split_store(w, ((k >> 3) * 512 + n) * 8 + (k & 7), pkhi, pkmd, pklo);
}

__global__ __launch_bounds__(256) void build_bias(
    const float* __restrict__ bihC, const float* __restrict__ bhhC,
    const float* __restrict__ WihC, const float* __restrict__ blc,
    const float* __restrict__ bihL, const float* __restrict__ bhhL,
    const float* __restrict__ WihL, const float* __restrict__ bcl,
    float* __restrict__ bsumC, float* __restrict__ bvecC,
    float* __restrict__ bsumL, float* __restrict__ bvecL) {
  int i = blockIdx.x * 256 + threadIdx.x;   // [0, 1024)
  if (i < 512) {
    bsumC[i] = bihC[i] + bhhC[i];
    float s = 0.f;
    for (int d = 0; d < 128; ++d) s += WihC[i * 128 + d] * blc[d];
    bvecC[i] = s;
  } else if (i < 1024) {
    int n = i - 512;
    bsumL[n] = bihL[n] + bhhL[n];
    float s = 0.f;
    for (int d = 0; d < 128; ++d) s += WihL[n * 256 + d] * bcl[d];
    bvecL[n] = s;
  }
}

// 6-term triple-split product: hh + hm + mh + hl + lh + mm  (error ~2^-27)
#define MFMA6(ACC, AH, AM, AL, BH, BM, BL)                                   \
  ACC = __builtin_amdgcn_mfma_f32_16x16x32_bf16(AH, BH, ACC, 0, 0, 0);       \
  ACC = __builtin_amdgcn_mfma_f32_16x16x32_bf16(AH, BM, ACC, 0, 0, 0);       \
  ACC = __builtin_amdgcn_mfma_f32_16x16x32_bf16(AM, BH, ACC, 0, 0, 0);       \
  ACC = __builtin_amdgcn_mfma_f32_16x16x32_bf16(AH, BL, ACC, 0, 0, 0);       \
  ACC = __builtin_amdgcn_mfma_f32_16x16x32_bf16(AL, BH, ACC, 0, 0, 0);       \
  ACC = __builtin_amdgcn_mfma_f32_16x16x32_bf16(AM, BM, ACC, 0, 0, 0);

// ---------------- fused MFMA step kernels ----------------
// Block: 32 rows, 512 threads (8 waves). Wave w owns output cols w*16..w*16+15 of all 4 gates.
// A (gather + states) in LDS as triple-split bf16 octets; B streams from L2.
// __launch_bounds__(512, 2): 256-VGPR cap — the (512,4)/128-cap variant spilled
// accumulators in the K-loop (R4 ran 6x over the L2-BW model).

__global__ __launch_bounds__(512, 2) void clause_mfma(
    const float* __restrict__ Lbuf, const int* __restrict__ csc, const int* __restrict__ ccnt,
    const unsigned short* __restrict__ pkhi, const unsigned short* __restrict__ pkmd,
    const unsigned short* __restrict__ pklo,
    const float* __restrict__ bsum, const float* __restrict__ bvec,
    float* __restrict__ hC, float* __restrict__ Cs) {
  __shared__ unsigned short A[3 * SPLIT];   // 50,688 B
  const int t = threadIdx.x;
  const int rowBase = blockIdx.x * 32;

  { // stage A: K = [msgs(128)=oct 0..15 | hC(128)=oct 16..31]
    const int r = t >> 4, sub = t & 15;
    const int c = rowBase + r;
    int cnt = ccnt[c]; int cl = cnt > COLW ? COLW : cnt;
    const int* lst = csc + c * COLW;
    float4 a0 = make_float4(0, 0, 0, 0), a1 = a0;
    for (int j = 0; j < cl; ++j) {
      const float4* s4 = (const float4*)(Lbuf + (size_t)lst[j] * DD + sub * 8);
      add4(a0, s4[0]); add4(a1, s4[1]);
    }
    store_oct3(A, sub, r, a0, a1);
    const float4* h4 = (const float4*)(hC + (size_t)c * DD + sub * 8);
    store_oct3(A, 16 + sub, r, h4[0], h4[1]);
  }
  __syncthreads();

  const int w = t >> 6, l = t & 63;
  const int quad = l >> 4, lane16 = l & 15;
  const int cw = w * 16 + lane16;   // output col 0..127
  f32x4 acc[2][4];
  #pragma unroll
  for (int mt = 0; mt < 2; ++mt)
    #pragma unroll
    for (int g = 0; g < 4; ++g) acc[mt][g] = (f32x4){0.f, 0.f, 0.f, 0.f};

  const short8* As = (const short8*)A;      // idx = oct*OS + m; splits at +SPLITS8
  const short8* Bh = (const short8*)pkhi;   // idx = oct*512 + n
  const short8* Bm = (const short8*)pkmd;
  const short8* Bl = (const short8*)pklo;

  #pragma unroll 2
  for (int s = 0; s < 8; ++s) {             // K=256
    int ao = (s * 4 + quad) * OS + lane16;
    short8 a0h = As[ao],                a1h = As[ao + 16];
    short8 a0m = As[SPLITS8 + ao],      a1m = As[SPLITS8 + ao + 16];
    short8 a0l = As[2 * SPLITS8 + ao],  a1l = As[2 * SPLITS8 + ao + 16];
    int bo = (s * 4 + quad) * 512 + cw;
    #pragma unroll
    for (int g = 0; g < 4; ++g) {
      short8 bh = Bh[bo + g * 128];
      short8 bm = Bm[bo + g * 128];
      short8 bl = Bl[bo + g * 128];
      MFMA6(acc[0][g], a0h, a0m, a0l, bh, bm, bl);
      MFMA6(acc[1][g], a1h, a1m, a1l, bh, bm, bl);
    }
  }

  float bs_[4], bv_[4];
  #pragma unroll
  for (int g = 0; g < 4; ++g) { bs_[g] = bsum[g * 128 + cw]; bv_[g] = bvec[g * 128 + cw]; }
  #pragma unroll
  for (int mt = 0; mt < 2; ++mt) {
    #pragma unroll
    for (int reg = 0; reg < 4; ++reg) {
      int row = rowBase + mt * 16 + quad * 4 + reg;
      float deg = (float)ccnt[row];
      float co = hC[(size_t)row * DD + cw];
      float iv = acc[mt][0][reg] + bs_[0] + deg * bv_[0];
      float fv = acc[mt][1][reg] + bs_[1] + deg * bv_[1];
      float gv = acc[mt][2][reg] + bs_[2] + deg * bv_[2];
      float ov = acc[mt][3][reg] + bs_[3] + deg * bv_[3];
      float cn = sigm(fv) * co + sigm(iv) * tanh_(gv);
      hC[(size_t)row * DD + cw] = cn;
      Cs[(size_t)row * DD + cw] = sigm(ov) * tanh_(cn);
    }
  }
}

__global__ __launch_bounds__(512, 2) void literal_mfma(
    const float* __restrict__ Cs, const int* __restrict__ csr, const int* __restrict__ rcnt,
    const unsigned short* __restrict__ pkhi, const unsigned short* __restrict__ pkmd,
    const unsigned short* __restrict__ pklo,
    const float* __restrict__ bsum, const float* __restrict__ bvec,
    float* __restrict__ hL, float* __restrict__ Lbuf) {
  __shared__ unsigned short A[3 * SPLIT];   // 50,688 B, two-phase K staging
  const int t = threadIdx.x;
  const int rowBase = blockIdx.x * 32;
  const int r = t >> 4, sub = t & 15;
  const int lr = rowBase + r;

  { // phase-1 stage: K 0..255 = [msgs(128)=oct 0..15 | L(128)=oct 16..31]
    int cnt = rcnt[lr]; int cl = cnt > ROWW ? ROWW : cnt;
    const int* lst = csr + lr * ROWW;
    float4 a0 = make_float4(0, 0, 0, 0), a1 = a0;
    for (int j = 0; j < cl; ++j) {
      const float4* s4 = (const float4*)(Cs + (size_t)lst[j] * DD + sub * 8);
      add4(a0, s4[0]); add4(a1, s4[1]);
    }
    store_oct3(A, sub, r, a0, a1);
    const float4* l4 = (const float4*)(Lbuf + (size_t)lr * DD + sub * 8);
    store_oct3(A, 16 + sub, r, l4[0], l4[1]);
  }
  __syncthreads();

  const int w = t >> 6, l = t & 63;
  const int quad = l >> 4, lane16 = l & 15;
  const int cw = w * 16 + lane16;
  f32x4 acc[2][4];
  #pragma unroll
  for (int mt = 0; mt < 2; ++mt)
    #pragma unroll
    for (int g = 0; g < 4; ++g) acc[mt][g] = (f32x4){0.f, 0.f, 0.f, 0.f};

  const short8* As = (const short8*)A;
  const short8* Bh = (const short8*)pkhi;
  const short8* Bm = (const short8*)pkmd;
  const short8* Bl = (const short8*)pklo;

  #pragma unroll 2
  for (int s = 0; s < 8; ++s) {             // K 0..255
    int ao = (s * 4 + quad) * OS + lane16;
    short8 a0h = As[ao],                a1h = As[ao + 16];
    short8 a0m = As[SPLITS8 + ao],      a1m = As[SPLITS8 + ao + 16];
    short8 a0l = As[2 * SPLITS8 + ao],  a1l = As[2 * SPLITS8 + ao + 16];
    int bo = (s * 4 + quad) * 512 + cw;
    #pragma unroll
    for (int g = 0; g < 4; ++g) {
      short8 bh = Bh[bo + g * 128];
      short8 bm = Bm[bo + g * 128];
      short8 bl = Bl[bo + g * 128];
      MFMA6(acc[0][g], a0h, a0m, a0l, bh, bm, bl);
      MFMA6(acc[1][g], a1h, a1m, a1l, bh, bm, bl);
    }
  }

  __syncthreads();   // all phase-1 LDS reads done
  { // phase-2 stage: hL -> octs 0..15 (reusing buffer)
    const float4* h4 = (const float4*)(hL + (size_t)lr * DD + sub * 8);
    store_oct3(A, sub, r, h4[0], h4[1]);
  }
  __syncthreads();

  #pragma unroll 2
  for (int s = 8; s < 12; ++s) {            // K 256..383 (hL)
    int ao = ((s - 8) * 4 + quad) * OS + lane16;
    short8 a0h = As[ao],                a1h = As[ao + 16];
    short8 a0m = As[SPLITS8 + ao],      a1m = As[SPLITS8 + ao + 16];
    short8 a0l = As[2 * SPLITS8 + ao],  a1l = As[2 * SPLITS8 + ao + 16];
    int bo = (s * 4 + quad) * 512 + cw;
    #pragma unroll
    for (int g = 0; g < 4; ++g) {
      short8 bh = Bh[bo + g * 128];
      short8 bm = Bm[bo + g * 128];
      short8 bl = Bl[bo + g * 128];
      MFMA6(acc[0][g], a0h, a0m, a0l, bh, bm, bl);
      MFMA6(acc[1][g], a1h, a1m, a1l, bh, bm, bl);
    }
  }

  float bs_[4], bv_[4];
  #pragma unroll
  for (int g = 0; g < 4; ++g) { bs_[g] = bsum[g * 128 + cw]; bv_[g] = bvec[g * 128 + cw]; }
  #pragma unroll
  for (int mt = 0; mt < 2; ++mt) {
    #pragma unroll
    for (int reg = 0; reg < 4; ++reg) {
      int row = rowBase + mt * 16 + quad * 4 + reg;
      float deg = (float)rcnt[row];
      float co = hL[(size_t)row * DD + cw];
      float iv = acc[mt][0][reg] + bs_[0] + deg * bv_[0];
      float fv = acc[mt][1][reg] + bs_[1] + deg * bv_[1];
      float gv = acc[mt][2][reg] + bs_[2] + deg * bv_[2];
      float ov = acc[mt][3][reg] + bs_[3] + deg * bv_[3];
      float cn = sigm(fv) * co + sigm(iv) * tanh_(gv);
      hL[(size_t)row * DD + cw] = cn;
      Lbuf[(size_t)row * DD + cw] = sigm(ov) * tanh_(cn);
    }
  }
}

// ---------------- launch ----------------

extern "C" void kernel_launch(void* const* d_in, const int* in_sizes, int n_in,
                              void* d_out, int out_size, void* d_ws, size_t ws_size,
                              hipStream_t stream) {
  const float* L0   = (const float*)d_in[0];
  // d_in[1] = C_state (unused), d_in[5] = n_vars (flip is identity)
  const float* hL0  = (const float*)d_in[2];
  const float* hC0  = (const float*)d_in[3];
  const float* M    = (const float*)d_in[4];
  const float* Wlc  = (const float*)d_in[6];
  const float* blc  = (const float*)d_in[7];
  const float* Wcl  = (const float*)d_in[8];
  const float* bcl  = (const float*)d_in[9];
  const float* WihC = (const float*)d_in[10];
  const float* WhhC = (const float*)d_in[11];
  const float* bihC = (const float*)d_in[12];
  const float* bhhC = (const float*)d_in[13];
  const float* WihL = (const float*)d_in[14];
  const float* WhhL = (const float*)d_in[15];
  const float* bihL = (const float*)d_in[16];
  const float* bhhL = (const float*)d_in[17];

  float* ws    = (float*)d_ws;
  float* hL    = ws;                         // NL*DD
  float* hC    = hL + NL * DD;               // NC*DD
  float* Cs    = hC + NC * DD;               // NC*DD
  float* bsumC = Cs + NC * DD;               // 512
  float* bvecC = bsumC + 512;
  float* bsumL = bvecC + 512;
  float* bvecL = bsumL + 512;
  unsigned short* pkChi = (unsigned short*)(bvecL + 512);   // 256*512 each
  unsigned short* pkCmd = pkChi + 256 * 512;
  unsigned short* pkClo = pkCmd + 256 * 512;
  unsigned short* pkLhi = pkClo + 256 * 512;                // 384*512 each
  unsigned short* pkLmd = pkLhi + 384 * 512;
  unsigned short* pkLlo = pkLmd + 384 * 512;
  int* csr  = (int*)(pkLlo + 384 * 512);     // NL*ROWW
  int* csc  = csr + NL * ROWW;               // NC*COLW
  int* rcnt = csc + NC * COLW;               // NL
  int* ccnt = rcnt + NL;                     // NC (contiguous with rcnt)
  float* Lbuf = (float*)d_out;               // literal state lives in d_out

  hipMemsetAsync(rcnt, 0, (NL + NC) * sizeof(int), stream);

  copy_f4<<<1024, 256, 0, stream>>>((float4*)Lbuf, (const float4*)L0,  NL * DD / 4);
  copy_f4<<<1024, 256, 0, stream>>>((float4*)hL,   (const float4*)hL0, NL * DD / 4);
  copy_f4<<<1024, 256, 0, stream>>>((float4*)hC,   (const float4*)hC0, NC * DD / 4);

  scan_M<<<4096, 256, 0, stream>>>((const float4*)M, csr, csc, rcnt, ccnt);

  build_packC<<<(256 * 512) / 256, 256, 0, stream>>>(WihC, Wlc, WhhC, pkChi, pkCmd, pkClo);
  build_packL<<<(384 * 512) / 256, 256, 0, stream>>>(WihL, Wcl, WhhL, pkLhi, pkLmd, pkLlo);
  build_bias<<<4, 256, 0, stream>>>(bihC, bhhC, WihC, blc, bihL, bhhL, WihL, bcl,
                                    bsumC, bvecC, bsumL, bvecL);

  for (int t = 0; t < TSTEPS; ++t) {
    clause_mfma<<<NC / 32, 512, 0, stream>>>(Lbuf, csc, ccnt, pkChi, pkCmd, pkClo,
                                             bsumC, bvecC, hC, Cs);
    literal_mfma<<<NL / 32, 512, 0, stream>>>(Cs, csr, rcnt, pkLhi, pkLmd, pkLlo,
                                              bsumL, bvecL, hL, Lbuf);
  }
}